// Round 4
// baseline (150.133 us; speedup 1.0000x reference)
//
#include <hip/hip_runtime.h>

// ISTA T=5, LAM=0.1, B=L=4096, K=128. Loop-invariant algebra:
//   u = corr(y - corr(y,h), rev(h));  x_final = 5 * soft_thresh(s*u, LAM)
// (closed form: su constant across the 5 steps, sign never flips).
// MFMA Toeplitz GEMM formulation (R3), plus R4:
//  - rs aliased into ys LDS buffer (r held in regs across one barrier):
//    LDS 48->26.4 KB, occupancy 3->4+ blocks/CU.
//  - uniform-branch fast paths for interior blocks (no per-elem bounds).
//  - conv1 padded to 44 tiles -> uniform unrolled 11 tiles/wave.

typedef __bf16 bf16;
typedef __bf16 bf16x4 __attribute__((ext_vector_type(4)));
typedef __bf16 bf16x8 __attribute__((ext_vector_type(8)));
typedef float f32x4 __attribute__((ext_vector_type(4)));

#define LC 512
#define PY 808   // row pitch (bf16): 404 dw, 404%32=20 -> 8 distinct bank offs
#define LAM 0.1f

__global__ __launch_bounds__(256, 4) void ista_mfma(
    const float* __restrict__ y, const float* __restrict__ h,
    const float* __restrict__ step, float* __restrict__ out) {
  __shared__ __align__(16) bf16 buf[16 * PY + 64];  // ys, later aliased as rs
  __shared__ float hs[128];

  const int tid = threadIdx.x;
  const int lane = tid & 63;
  const int wave = tid >> 6;
  const int li = lane & 15;   // A-row i AND B/C column b
  const int quad = lane >> 4;
  const int chunk0 = blockIdx.x * LC;
  const int b0 = blockIdx.y * 16;

  if (tid < 128) hs[tid] = h[tid];

  // ---- stage y (fp32 -> bf16 LDS), cols [chunk0-128, chunk0+672) ----
  {
    const int rr = tid >> 4;
    const int t = tid & 15;
    const float* yrow = y + (size_t)(b0 + rr) * 4096 + (chunk0 - 128);
    bf16* dst = buf + rr * PY;
    if (chunk0 >= 128 && chunk0 + 672 <= 4096) {   // interior: no checks
      for (int s4 = t; s4 < 200; s4 += 16) {
        float4 v = *reinterpret_cast<const float4*>(yrow + s4 * 4);
        bf16x4 bv;
        bv[0] = (bf16)v.x; bv[1] = (bf16)v.y;
        bv[2] = (bf16)v.z; bv[3] = (bf16)v.w;
        *reinterpret_cast<bf16x4*>(dst + s4 * 4) = bv;
      }
    } else {
      for (int s4 = t; s4 < 200; s4 += 16) {
        int l = chunk0 - 128 + s4 * 4;
        float4 v;
        v.x = (l + 0 >= 0 && l + 0 < 4096) ? yrow[s4 * 4 + 0] : 0.f;
        v.y = (l + 1 >= 0 && l + 1 < 4096) ? yrow[s4 * 4 + 1] : 0.f;
        v.z = (l + 2 >= 0 && l + 2 < 4096) ? yrow[s4 * 4 + 2] : 0.f;
        v.w = (l + 3 >= 0 && l + 3 < 4096) ? yrow[s4 * 4 + 3] : 0.f;
        bf16x4 bv;
        bv[0] = (bf16)v.x; bv[1] = (bf16)v.y;
        bv[2] = (bf16)v.z; bv[3] = (bf16)v.w;
        *reinterpret_cast<bf16x4*>(dst + s4 * 4) = bv;
      }
    }
  }
  __syncthreads();

  // ---- wave-uniform Toeplitz A-fragments: A[m=li][k=quad*8+j] ----
  // conv1: T1[i][j] = h[j - i + 63];  conv2 (negated): -h[64 + i - j].
  bf16x8 A1[5], A2[5];
#pragma unroll
  for (int dd = 0; dd < 5; ++dd) {
    int d = (dd - 2) * 32;
    bf16x8 a1, a2;
#pragma unroll
    for (int j = 0; j < 8; ++j) {
      int k = quad * 8 + j;
      int idx1 = 63 + d + k - li;
      a1[j] = (idx1 >= 0 && idx1 < 128) ? (bf16)hs[idx1] : (bf16)0.f;
      int idx2 = 64 + li - d - k;
      a2[j] = (idx2 >= 0 && idx2 < 128) ? (bf16)(-hs[idx2]) : (bf16)0.f;
    }
    A1[dd] = a1; A2[dd] = a2;
  }

  // ---- conv1: 44 tiles (41 real + 3 junk into unread slack), 11/wave ----
  // acc init = -y => emits -r; tile result held in regs as bf16x4.
  bf16x4 rv[11];
  const bool edge = (chunk0 == 0) || (chunk0 + LC == 4096);
#pragma unroll
  for (int i = 0; i < 11; ++i) {
    const int t = wave + 4 * i;
    const int i0 = -64 + 16 * t;
    const bf16* base = buf + li * PY + (i0 + 128);
    f32x4 acc;
    {
      bf16x4 yv = *reinterpret_cast<const bf16x4*>(base + quad * 4);
      acc[0] = -(float)yv[0]; acc[1] = -(float)yv[1];
      acc[2] = -(float)yv[2]; acc[3] = -(float)yv[3];
    }
#pragma unroll
    for (int dd = 0; dd < 5; ++dd) {
      bf16x8 bfrag = *reinterpret_cast<const bf16x8*>(
          base + (dd - 2) * 32 + quad * 8);
      acc = __builtin_amdgcn_mfma_f32_16x16x32_bf16(A1[dd], bfrag, acc, 0, 0, 0);
    }
    if (edge) {
#pragma unroll
      for (int e = 0; e < 4; ++e) {
        int g = chunk0 + i0 + quad * 4 + e;
        rv[i][e] = (bf16)((g >= 0 && g < 4096) ? acc[e] : 0.f);
      }
    } else {
#pragma unroll
      for (int e = 0; e < 4; ++e) rv[i][e] = (bf16)acc[e];
    }
  }
  __syncthreads();   // all ys reads done -> safe to alias

  // ---- write -r into aliased buffer: rs float-index q <-> col q-64 ----
#pragma unroll
  for (int i = 0; i < 11; ++i) {
    const int t = wave + 4 * i;
    const int i0 = -64 + 16 * t;
    *reinterpret_cast<bf16x4*>(buf + li * PY + (i0 + 64) + quad * 4) = rv[i];
  }
  __syncthreads();

  // ---- conv2 + closed-form soft-threshold epilogue: 32 tiles, 8/wave ----
  const float s = step[0];
#pragma unroll
  for (int i = 0; i < 8; ++i) {
    const int t = wave + 4 * i;
    const int i0 = 16 * t;
    const bf16* base = buf + li * PY + (i0 + 64);
    f32x4 acc = {0.f, 0.f, 0.f, 0.f};
#pragma unroll
    for (int dd = 0; dd < 5; ++dd) {
      bf16x8 bfrag = *reinterpret_cast<const bf16x8*>(
          base + (dd - 2) * 32 + quad * 8);
      acc = __builtin_amdgcn_mfma_f32_16x16x32_bf16(A2[dd], bfrag, acc, 0, 0, 0);
    }
    float4 xv;
#pragma unroll
    for (int e = 0; e < 4; ++e) {
      float su = s * acc[e];
      float ax = fmaxf(fabsf(su) - LAM, 0.f);
      (&xv.x)[e] = copysignf(5.f * ax, su);
    }
    *reinterpret_cast<float4*>(
        out + (size_t)(b0 + li) * 4096 + chunk0 + i0 + quad * 4) = xv;
  }
}

extern "C" void kernel_launch(void* const* d_in, const int* in_sizes, int n_in,
                              void* d_out, int out_size, void* d_ws,
                              size_t ws_size, hipStream_t stream) {
  const float* y = (const float*)d_in[0];
  const float* h = (const float*)d_in[1];
  const float* s = (const float*)d_in[2];
  float* out = (float*)d_out;
  ista_mfma<<<dim3(4096 / LC, 256), dim3(256), 0, stream>>>(y, h, s, out);
}